// Round 1
// baseline (182.869 us; speedup 1.0000x reference)
//
#include <hip/hip_runtime.h>

// Problem: mean((  (model-cur)/3  - 0.0257*Laplacian3D(cur)  - src(cur) )^2)
// Shapes: [B=8, C=1, D=128, H=128, W=128], f32. Zero-padded 7-point stencil.

constexpr int BATCH = 8;
constexpr int DD = 128;
constexpr int HH = 128;
constexpr int WW = 128;
constexpr long long N_ELEM = (long long)BATCH * DD * HH * WW;   // 16,777,216
constexpr int N_VEC = (int)(N_ELEM / 4);                         // 4,194,304

constexpr float ALPHA  = 0.0257f;
constexpr float INV_DT = 1.0f / 3.0f;
constexpr float SRC_I  = 100000.0f;
constexpr float THRESH = 1000.0f;

__global__ void zero_acc_kernel(double* acc) {
    if (threadIdx.x == 0 && blockIdx.x == 0) acc[0] = 0.0;
}

__global__ __launch_bounds__(256) void heat_loss_kernel(
        const float* __restrict__ model,
        const float* __restrict__ cur,
        double* __restrict__ acc_out) {
    const int tid = blockIdx.x * blockDim.x + threadIdx.x;
    const int nth = gridDim.x * blockDim.x;

    float acc = 0.0f;

    for (int v = tid; v < N_VEC; v += nth) {
        const int x4 = v & 31;           // W/4 = 32 vec-positions per row
        int rest = v >> 5;
        const int y = rest & 127;
        rest >>= 7;
        const int z = rest & 127;
        // batch index only matters through the flat address

        const int i = v * 4;             // flat element index (fits in int)

        const float4 c = *reinterpret_cast<const float4*>(cur + i);
        const float4 m = *reinterpret_cast<const float4*>(model + i);

        // x-neighbors: shifted window with zero pad at row edges
        const float left  = (x4 == 0)  ? 0.0f : cur[i - 1];
        const float right = (x4 == 31) ? 0.0f : cur[i + 4];

        const float4 zero4 = make_float4(0.f, 0.f, 0.f, 0.f);
        const float4 ym = (y == 0)   ? zero4 : *reinterpret_cast<const float4*>(cur + i - WW);
        const float4 yp = (y == 127) ? zero4 : *reinterpret_cast<const float4*>(cur + i + WW);
        const float4 zm = (z == 0)   ? zero4 : *reinterpret_cast<const float4*>(cur + i - HH * WW);
        const float4 zp = (z == 127) ? zero4 : *reinterpret_cast<const float4*>(cur + i + HH * WW);

        const float cc[4] = {c.x, c.y, c.z, c.w};
        const float mm[4] = {m.x, m.y, m.z, m.w};
        const float xs[6] = {left, c.x, c.y, c.z, c.w, right};
        const float yms[4] = {ym.x, ym.y, ym.z, ym.w};
        const float yps[4] = {yp.x, yp.y, yp.z, yp.w};
        const float zms[4] = {zm.x, zm.y, zm.z, zm.w};
        const float zps[4] = {zp.x, zp.y, zp.z, zp.w};

        #pragma unroll
        for (int j = 0; j < 4; ++j) {
            const float lap = xs[j] + xs[j + 2] + yms[j] + yps[j]
                            + zms[j] + zps[j] - 6.0f * cc[j];
            const float td  = (mm[j] - cc[j]) * INV_DT;
            const float src = (cc[j] > THRESH) ? SRC_I : 0.0f;
            const float r   = td - ALPHA * lap - src;
            acc = fmaf(r, r, acc);
        }
    }

    // wave (64-lane) reduction
    #pragma unroll
    for (int off = 32; off > 0; off >>= 1)
        acc += __shfl_down(acc, off, 64);

    __shared__ float wsum[4];            // 256 threads / 64 = 4 waves
    const int lane = threadIdx.x & 63;
    const int wave = threadIdx.x >> 6;
    if (lane == 0) wsum[wave] = acc;
    __syncthreads();

    if (threadIdx.x == 0) {
        const float s = wsum[0] + wsum[1] + wsum[2] + wsum[3];
        atomicAdd(acc_out, (double)s);   // one device-scope f64 atomic per block
    }
}

__global__ void finalize_kernel(const double* __restrict__ acc, float* __restrict__ out) {
    if (threadIdx.x == 0 && blockIdx.x == 0)
        out[0] = (float)(acc[0] / (double)N_ELEM);
}

extern "C" void kernel_launch(void* const* d_in, const int* in_sizes, int n_in,
                              void* d_out, int out_size, void* d_ws, size_t ws_size,
                              hipStream_t stream) {
    const float* model = (const float*)d_in[0];   // model_output
    const float* cur   = (const float*)d_in[1];   // current_input
    double* acc = (double*)d_ws;                  // 8 bytes of scratch
    float*  out = (float*)d_out;

    zero_acc_kernel<<<1, 1, 0, stream>>>(acc);
    heat_loss_kernel<<<2048, 256, 0, stream>>>(model, cur, acc);
    finalize_kernel<<<1, 1, 0, stream>>>(acc, out);
}